// Round 1
// baseline (191.055 us; speedup 1.0000x reference)
//
#include <hip/hip_runtime.h>

typedef __bf16 bf16;
typedef __attribute__((ext_vector_type(8))) __bf16 bf16x8;
typedef __attribute__((ext_vector_type(4))) float f32x4;

#define MFMA16(a, b, c) __builtin_amdgcn_mfma_f32_16x16x32_bf16((a), (b), (c), 0, 0, 0)

// ---------------------------------------------------------------------------
// Kernel 1: transpose W [o][c] -> Wt [c][o] fp32 (selects Wq for K if flag)
// grid: (16, 2) x 256 threads, 4 elements/thread
// ---------------------------------------------------------------------------
__global__ __launch_bounds__(256) void prep_w_kernel(const float* __restrict__ Wq,
                                                     const float* __restrict__ Wk,
                                                     const int* __restrict__ flag,
                                                     float* __restrict__ Wtq,
                                                     float* __restrict__ Wtk) {
  const int z = blockIdx.y;
  const float* src = (z == 0) ? Wq : ((flag[0] != 0) ? Wq : Wk);
  float* dst = (z == 0) ? Wtq : Wtk;
  int i = (blockIdx.x * 256 + threadIdx.x) * 4;  // 0..16383
  int o = i >> 8, c0 = i & 255;
  float4 v = *(const float4*)(src + o * 256 + c0);
  dst[(c0 + 0) * 64 + o] = v.x;
  dst[(c0 + 1) * 64 + o] = v.y;
  dst[(c0 + 2) * 64 + o] = v.z;
  dst[(c0 + 3) * 64 + o] = v.w;
}

// ---------------------------------------------------------------------------
// Kernel 2: 1x1-conv projections, fp32 accumulate, bf16 store.
// grid: (32 p-tiles, 32 batches, 2 {Q,K}) x 256 threads.
// Thread (p = t>>3 within 32-pixel tile, og = t&7 -> 8 output channels).
// ---------------------------------------------------------------------------
__global__ __launch_bounds__(256) void proj_kernel(const float* __restrict__ qf,
                                                   const float* __restrict__ kf,
                                                   const float* __restrict__ Wtq,
                                                   const float* __restrict__ Wtk,
                                                   const float* __restrict__ bq,
                                                   const float* __restrict__ bk,
                                                   const int* __restrict__ flag,
                                                   bf16* __restrict__ Qp,
                                                   bf16* __restrict__ Kp) {
  const int b = blockIdx.y, z = blockIdx.z;
  const int p0 = blockIdx.x * 32;
  const float* x = z ? kf : qf;
  const float* W = z ? Wtk : Wtq;
  const float* bias = z ? (flag[0] ? bq : bk) : bq;
  bf16* dst = z ? Kp : Qp;

  __shared__ float sX[256 * 32];  // [c][p] tile, 32 KB
  const int t = threadIdx.x;
#pragma unroll
  for (int it = 0; it < 32; ++it) {
    int task = it * 256 + t;  // task = c*32 + pp
    int c = task >> 5, pp = task & 31;
    sX[task] = x[(((b << 8) + c) << 10) + p0 + pp];
  }
  __syncthreads();

  const int og = t & 7, p = t >> 3;
  float acc[8];
  {
    float4 b0 = *(const float4*)(bias + og * 8);
    float4 b1 = *(const float4*)(bias + og * 8 + 4);
    acc[0] = b0.x; acc[1] = b0.y; acc[2] = b0.z; acc[3] = b0.w;
    acc[4] = b1.x; acc[5] = b1.y; acc[6] = b1.z; acc[7] = b1.w;
  }
  for (int c = 0; c < 256; ++c) {
    float xv = sX[(c << 5) + p];
    float4 w0 = *(const float4*)(W + (c << 6) + og * 8);
    float4 w1 = *(const float4*)(W + (c << 6) + og * 8 + 4);
    acc[0] = fmaf(xv, w0.x, acc[0]);
    acc[1] = fmaf(xv, w0.y, acc[1]);
    acc[2] = fmaf(xv, w0.z, acc[2]);
    acc[3] = fmaf(xv, w0.w, acc[3]);
    acc[4] = fmaf(xv, w1.x, acc[4]);
    acc[5] = fmaf(xv, w1.y, acc[5]);
    acc[6] = fmaf(xv, w1.z, acc[6]);
    acc[7] = fmaf(xv, w1.w, acc[7]);
  }
  bf16x8 o8;
#pragma unroll
  for (int j = 0; j < 8; ++j) o8[j] = (bf16)acc[j];
  *(bf16x8*)(dst + (((b << 10) + p0 + p) << 6) + og * 8) = o8;
}

// ---------------------------------------------------------------------------
// Kernel 3: fused flash attention. grid (16 p-tiles, 32 batches) x 256 thr.
// p-tile = 64 rows. Wave w: S+softmax for rows [16w,16w+16); PV for channel
// slice [64w, 64w+64). K/V/P staged in XOR-swizzled LDS.
// ---------------------------------------------------------------------------
__global__ __launch_bounds__(256, 2) void attn_kernel(const float* __restrict__ kf,
                                                      const bf16* __restrict__ Qp,
                                                      const bf16* __restrict__ Kp,
                                                      float* __restrict__ out) {
  const int b = blockIdx.y;
  const int p0 = blockIdx.x << 6;
  const int t = threadIdx.x;
  const int w = t >> 6, lane = t & 63;
  const int g = lane >> 4, l16 = lane & 15;

  __shared__ __align__(16) unsigned char smem[66560];
  __shared__ float sSc[64];
  __shared__ float sL[64];
  unsigned char* sK = smem;          // [64 q][64 o] bf16, 128B rows, swizzled
  unsigned char* sV = smem + 8192;   // [256 c][64 q] bf16, swizzled
  unsigned char* sP = smem + 40960;  // [64 row][64 q] bf16, swizzled

  // Q fragments for this wave's 16 rows (A-operand: row=l16, k=8*g+j)
  bf16x8 aq0, aq1;
  {
    const int prow = p0 + (w << 4) + l16;
    const bf16* qb = Qp + (((b << 10) + prow) << 6) + (g << 3);
    aq0 = *(const bf16x8*)qb;
    aq1 = *(const bf16x8*)(qb + 32);
  }

  f32x4 acc[4][4];  // [row-group][channel-sub]
#pragma unroll
  for (int i = 0; i < 4; ++i)
#pragma unroll
    for (int j = 0; j < 4; ++j) acc[i][j] = (f32x4){0.f, 0.f, 0.f, 0.f};
  float m_[4], l_[4];
#pragma unroll
  for (int r = 0; r < 4; ++r) { m_[r] = -1e30f; l_[r] = 0.f; }

  for (int kt = 0; kt < 16; ++kt) {
    const int q0 = kt << 6;
    __syncthreads();  // (A) previous tile's LDS reads complete
    // ---- stage K tile: 64q x 64o bf16 (8 KB) ----
#pragma unroll
    for (int it = 0; it < 2; ++it) {
      int task = it * 256 + t;
      int q = task >> 3, oc = task & 7;
      bf16x8 v = *(const bf16x8*)(Kp + (((b << 10) + q0 + q) << 6) + (oc << 3));
      *(bf16x8*)(sK + ((q * 128 + oc * 16) ^ ((q & 7) << 4))) = v;
    }
    // ---- stage V tile: 256c x 64q fp32 -> bf16 (32 KB) ----
#pragma unroll
    for (int it = 0; it < 8; ++it) {
      int task = it * 256 + t;
      int c = task >> 3, qc = task & 7;
      const float* vp = kf + (((b << 8) + c) << 10) + q0 + (qc << 3);
      float4 f0 = *(const float4*)vp;
      float4 f1 = *(const float4*)(vp + 4);
      bf16x8 vb;
      vb[0] = (bf16)f0.x; vb[1] = (bf16)f0.y; vb[2] = (bf16)f0.z; vb[3] = (bf16)f0.w;
      vb[4] = (bf16)f1.x; vb[5] = (bf16)f1.y; vb[6] = (bf16)f1.z; vb[7] = (bf16)f1.w;
      *(bf16x8*)(sV + ((c * 128 + qc * 16) ^ ((c & 7) << 4))) = vb;
    }
    __syncthreads();  // (B) staging visible

    // ---- S = Q K^T for this wave's 16 rows ----
    f32x4 s[4];
#pragma unroll
    for (int qf = 0; qf < 4; ++qf) {
      int q = (qf << 4) + l16;
      bf16x8 k0 = *(const bf16x8*)(sK + ((q * 128 + g * 16) ^ ((q & 7) << 4)));
      bf16x8 k1 = *(const bf16x8*)(sK + ((q * 128 + g * 16 + 64) ^ ((q & 7) << 4)));
      f32x4 z4 = (f32x4){0.f, 0.f, 0.f, 0.f};
      z4 = MFMA16(aq0, k0, z4);
      s[qf] = MFMA16(aq1, k1, z4);
    }
    // ---- online softmax (rows 16w + 4g + r) ----
    float tm[4], sc[4], rs[4];
#pragma unroll
    for (int r = 0; r < 4; ++r) {
      tm[r] = fmaxf(fmaxf(s[0][r], s[1][r]), fmaxf(s[2][r], s[3][r]));
      tm[r] = fmaxf(tm[r], __shfl_xor(tm[r], 1));
      tm[r] = fmaxf(tm[r], __shfl_xor(tm[r], 2));
      tm[r] = fmaxf(tm[r], __shfl_xor(tm[r], 4));
      tm[r] = fmaxf(tm[r], __shfl_xor(tm[r], 8));
      float mn = fmaxf(m_[r], tm[r]);
      sc[r] = __expf(m_[r] - mn);
      m_[r] = mn;
    }
#pragma unroll
    for (int qf = 0; qf < 4; ++qf)
#pragma unroll
      for (int r = 0; r < 4; ++r) s[qf][r] = __expf(s[qf][r] - m_[r]);
#pragma unroll
    for (int r = 0; r < 4; ++r) {
      rs[r] = (s[0][r] + s[1][r]) + (s[2][r] + s[3][r]);
      rs[r] += __shfl_xor(rs[r], 1);
      rs[r] += __shfl_xor(rs[r], 2);
      rs[r] += __shfl_xor(rs[r], 4);
      rs[r] += __shfl_xor(rs[r], 8);
      l_[r] = l_[r] * sc[r] + rs[r];
    }
    // ---- publish P (bf16) and per-row rescale factors ----
    if (l16 == 0) {
#pragma unroll
      for (int r = 0; r < 4; ++r) sSc[(w << 4) + (g << 2) + r] = sc[r];
    }
#pragma unroll
    for (int qf = 0; qf < 4; ++qf)
#pragma unroll
      for (int r = 0; r < 4; ++r) {
        int row = (w << 4) + (g << 2) + r;
        int col = (qf << 4) + l16;
        *(bf16*)(sP + ((row * 128 + col * 2) ^ ((row & 7) << 4))) = (bf16)s[qf][r];
      }
    __syncthreads();  // (C) P + scales visible to all waves

    // ---- rescale accumulators ----
#pragma unroll
    for (int rg = 0; rg < 4; ++rg) {
      float f0 = sSc[(rg << 4) + (g << 2) + 0];
      float f1 = sSc[(rg << 4) + (g << 2) + 1];
      float f2 = sSc[(rg << 4) + (g << 2) + 2];
      float f3 = sSc[(rg << 4) + (g << 2) + 3];
#pragma unroll
      for (int cl = 0; cl < 4; ++cl) {
        acc[rg][cl][0] *= f0;
        acc[rg][cl][1] *= f1;
        acc[rg][cl][2] *= f2;
        acc[rg][cl][3] *= f3;
      }
    }
    // ---- load P A-fragments (all 64 rows) ----
    bf16x8 pa[4][2];
#pragma unroll
    for (int rg = 0; rg < 4; ++rg) {
      int row = (rg << 4) + l16;
      pa[rg][0] = *(const bf16x8*)(sP + ((row * 128 + g * 16) ^ ((row & 7) << 4)));
      pa[rg][1] = *(const bf16x8*)(sP + ((row * 128 + g * 16 + 64) ^ ((row & 7) << 4)));
    }
    // ---- PV: this wave's 64-channel slice ----
#pragma unroll
    for (int cl = 0; cl < 4; ++cl) {
      int c = (w << 6) + (cl << 4) + l16;
      bf16x8 v0 = *(const bf16x8*)(sV + ((c * 128 + g * 16) ^ ((c & 7) << 4)));
      bf16x8 v1 = *(const bf16x8*)(sV + ((c * 128 + g * 16 + 64) ^ ((c & 7) << 4)));
#pragma unroll
      for (int rg = 0; rg < 4; ++rg) {
        acc[rg][cl] = MFMA16(pa[rg][0], v0, acc[rg][cl]);
        acc[rg][cl] = MFMA16(pa[rg][1], v1, acc[rg][cl]);
      }
    }
  }

  // ---- epilogue: normalize, transpose via LDS, coalesced store ----
  if (l16 == 0) {
#pragma unroll
    for (int r = 0; r < 4; ++r) sL[(w << 4) + (g << 2) + r] = l_[r];
  }
  __syncthreads();  // also protects smem reuse below
  float* sO = (float*)smem;  // [c][65] padded
#pragma unroll
  for (int rg = 0; rg < 4; ++rg) {
    float i0 = 1.f / sL[(rg << 4) + (g << 2) + 0];
    float i1 = 1.f / sL[(rg << 4) + (g << 2) + 1];
    float i2 = 1.f / sL[(rg << 4) + (g << 2) + 2];
    float i3 = 1.f / sL[(rg << 4) + (g << 2) + 3];
    int rowb = (rg << 4) + (g << 2);
#pragma unroll
    for (int cl = 0; cl < 4; ++cl) {
      int c = (w << 6) + (cl << 4) + l16;
      sO[c * 65 + rowb + 0] = acc[rg][cl][0] * i0;
      sO[c * 65 + rowb + 1] = acc[rg][cl][1] * i1;
      sO[c * 65 + rowb + 2] = acc[rg][cl][2] * i2;
      sO[c * 65 + rowb + 3] = acc[rg][cl][3] * i3;
    }
  }
  __syncthreads();
#pragma unroll
  for (int it = 0; it < 16; ++it) {
    int c = (it << 4) + (t >> 4);
    int p4 = (t & 15) << 2;
    float4 v;
    v.x = sO[c * 65 + p4 + 0];
    v.y = sO[c * 65 + p4 + 1];
    v.z = sO[c * 65 + p4 + 2];
    v.w = sO[c * 65 + p4 + 3];
    *(float4*)(out + (((b << 8) + c) << 10) + p0 + p4) = v;
  }
}

// ---------------------------------------------------------------------------
extern "C" void kernel_launch(void* const* d_in, const int* in_sizes, int n_in,
                              void* d_out, int out_size, void* d_ws, size_t ws_size,
                              hipStream_t stream) {
  const float* qf = (const float*)d_in[0];
  const float* kf = (const float*)d_in[1];
  const float* Wq = (const float*)d_in[2];
  const float* bq = (const float*)d_in[3];
  const float* Wk = (const float*)d_in[4];
  const float* bk = (const float*)d_in[5];
  // d_in[6] = vis_CA (unused)
  const int* flag = (const int*)d_in[7];  // same_WqWk
  float* out = (float*)d_out;

  char* ws = (char*)d_ws;
  bf16* Qp = (bf16*)ws;                          // 4 MiB: [32][1024][64] bf16
  bf16* Kp = (bf16*)(ws + (4u << 20));           // 4 MiB
  float* Wtq = (float*)(ws + (8u << 20));        // 64 KiB: [256][64] fp32
  float* Wtk = (float*)(ws + (8u << 20) + 65536);

  prep_w_kernel<<<dim3(16, 2), 256, 0, stream>>>(Wq, Wk, flag, Wtq, Wtk);
  proj_kernel<<<dim3(32, 32, 2), 256, 0, stream>>>(qf, kf, Wtq, Wtk, bq, bk, flag, Qp, Kp);
  attn_kernel<<<dim3(16, 32), 256, 0, stream>>>(kf, Qp, Kp, out);
}

// Round 2
// 90.711 us; speedup vs baseline: 2.1062x; 2.1062x over previous
//
#include <hip/hip_runtime.h>

typedef __bf16 bf16;
typedef __attribute__((ext_vector_type(4))) __bf16 bf16x4;
typedef __attribute__((ext_vector_type(8))) __bf16 bf16x8;
typedef __attribute__((ext_vector_type(4))) float f32x4;

#define MFMA16(a, b, c) __builtin_amdgcn_mfma_f32_16x16x32_bf16((a), (b), (c), 0, 0, 0)

// ---------------------------------------------------------------------------
// Kernel 1: W [o][c] fp32 -> hi/lo bf16 split, same [o][c] layout.
// z=0: Wq ; z=1: (flag ? Wq : Wk). grid (16, 2) x 256 threads, 4 elem/thread.
// ---------------------------------------------------------------------------
__global__ __launch_bounds__(256) void prep_w_kernel(const float* __restrict__ Wq,
                                                     const float* __restrict__ Wk,
                                                     const int* __restrict__ flag,
                                                     bf16* __restrict__ Wbh,
                                                     bf16* __restrict__ Wbl) {
  const int z = blockIdx.y;
  const float* src = (z == 0) ? Wq : ((flag[0] != 0) ? Wq : Wk);
  int i = (blockIdx.x * 256 + threadIdx.x) * 4;  // 0..16383
  float4 v = *(const float4*)(src + i);
  bf16x4 hi, lo;
  hi[0] = (bf16)v.x; lo[0] = (bf16)(v.x - (float)hi[0]);
  hi[1] = (bf16)v.y; lo[1] = (bf16)(v.y - (float)hi[1]);
  hi[2] = (bf16)v.z; lo[2] = (bf16)(v.z - (float)hi[2]);
  hi[3] = (bf16)v.w; lo[3] = (bf16)(v.w - (float)hi[3]);
  *(bf16x4*)(Wbh + z * 16384 + i) = hi;
  *(bf16x4*)(Wbl + z * 16384 + i) = lo;
}

// ---------------------------------------------------------------------------
// Kernel 2: MFMA projection. out[b][p][o] = sum_c x[b][c][p] * W[o][c] + bias.
// A = W (hi+lo bf16 split), B = x (fp32 loaded per-lane, cvt to bf16).
// grid (8 p-tiles of 128, 32 b, 2 z) x 256 thr (4 waves: 2 o-halves x 2 p-halves)
// ---------------------------------------------------------------------------
__global__ __launch_bounds__(256) void proj_kernel(const float* __restrict__ qf,
                                                   const float* __restrict__ kf,
                                                   const bf16* __restrict__ Wbh,
                                                   const bf16* __restrict__ Wbl,
                                                   const float* __restrict__ bq,
                                                   const float* __restrict__ bk,
                                                   const int* __restrict__ flag,
                                                   bf16* __restrict__ Qp,
                                                   bf16* __restrict__ Kp) {
  const int b = blockIdx.y, z = blockIdx.z;
  const float* x = z ? kf : qf;
  const bf16* Wh = Wbh + z * 16384;
  const bf16* Wl = Wbl + z * 16384;
  const float* bias = z ? (flag[0] ? bq : bk) : bq;
  bf16* dst = z ? Kp : Qp;

  const int t = threadIdx.x;
  const int w = t >> 6, lane = t & 63;
  const int g = lane >> 4, l16 = lane & 15;
  const int wo = w >> 1, wp = w & 1;
  const int o0 = wo << 5;                           // 32-channel half
  const int pbase = (blockIdx.x << 7) + (wp << 6);  // 64-pixel half

  // accumulators: [o-tile 0..1][p-tile 0..3], init with bias (row r -> o=o0+16ot+4g+r)
  f32x4 acc[2][4];
#pragma unroll
  for (int ot = 0; ot < 2; ++ot) {
    float4 bv = *(const float4*)(bias + o0 + (ot << 4) + (g << 2));
#pragma unroll
    for (int pt = 0; pt < 4; ++pt) acc[ot][pt] = (f32x4){bv.x, bv.y, bv.z, bv.w};
  }

  const float* xb = x + ((((b << 8) + (g << 3)) << 10) + pbase + l16);
  const bf16* whb = Wh + ((o0 + l16) << 8) + (g << 3);
  const bf16* wlb = Wl + ((o0 + l16) << 8) + (g << 3);

  for (int kk = 0; kk < 8; ++kk) {
    // A-fragments (W hi/lo), lane: row o = o0+16ot+l16, k = kk*32 + 8g + j
    bf16x8 ah[2], al[2];
#pragma unroll
    for (int ot = 0; ot < 2; ++ot) {
      ah[ot] = *(const bf16x8*)(whb + (ot << 12) + (kk << 5));
      al[ot] = *(const bf16x8*)(wlb + (ot << 12) + (kk << 5));
    }
    const float* xk = xb + (kk << 15);  // + kk*32*1024
#pragma unroll
    for (int pt = 0; pt < 4; ++pt) {
      // B-fragment: col p = pbase+16pt+l16, k = kk*32 + 8g + j
      float xv[8];
#pragma unroll
      for (int j = 0; j < 8; ++j) xv[j] = xk[(j << 10) + (pt << 4)];
      bf16x8 xf;
#pragma unroll
      for (int j = 0; j < 8; ++j) xf[j] = (bf16)xv[j];
#pragma unroll
      for (int ot = 0; ot < 2; ++ot) {
        acc[ot][pt] = MFMA16(ah[ot], xf, acc[ot][pt]);
        acc[ot][pt] = MFMA16(al[ot], xf, acc[ot][pt]);
      }
    }
  }

  // store: C/D lane holds col p=l16(+16pt), rows o = o0+16ot+4g+r (r contiguous)
#pragma unroll
  for (int ot = 0; ot < 2; ++ot)
#pragma unroll
    for (int pt = 0; pt < 4; ++pt) {
      bf16x4 q4;
#pragma unroll
      for (int r = 0; r < 4; ++r) q4[r] = (bf16)acc[ot][pt][r];
      int p = pbase + (pt << 4) + l16;
      *(bf16x4*)(dst + (((b << 10) + p) << 6) + o0 + (ot << 4) + (g << 2)) = q4;
    }
}

// ---------------------------------------------------------------------------
// Kernel 3: fused flash attention. grid (16 p-tiles, 32 batches) x 256 thr.
// p-tile = 64 rows. Wave w: S+softmax for rows [16w,16w+16); PV for channel
// slice [64w, 64w+64). K/V/P staged in XOR-swizzled LDS.
// ---------------------------------------------------------------------------
__global__ __launch_bounds__(256, 2) void attn_kernel(const float* __restrict__ kf,
                                                      const bf16* __restrict__ Qp,
                                                      const bf16* __restrict__ Kp,
                                                      float* __restrict__ out) {
  const int b = blockIdx.y;
  const int p0 = blockIdx.x << 6;
  const int t = threadIdx.x;
  const int w = t >> 6, lane = t & 63;
  const int g = lane >> 4, l16 = lane & 15;

  __shared__ __align__(16) unsigned char smem[66560];
  __shared__ float sSc[64];
  __shared__ float sL[64];
  unsigned char* sK = smem;          // [64 q][64 o] bf16, 128B rows, swizzled
  unsigned char* sV = smem + 8192;   // [256 c][64 q] bf16, swizzled
  unsigned char* sP = smem + 40960;  // [64 row][64 q] bf16, swizzled

  // Q fragments for this wave's 16 rows (A-operand: row=l16, k=8*g+j)
  bf16x8 aq0, aq1;
  {
    const int prow = p0 + (w << 4) + l16;
    const bf16* qb = Qp + (((b << 10) + prow) << 6) + (g << 3);
    aq0 = *(const bf16x8*)qb;
    aq1 = *(const bf16x8*)(qb + 32);
  }

  f32x4 acc[4][4];  // [row-group][channel-sub]
#pragma unroll
  for (int i = 0; i < 4; ++i)
#pragma unroll
    for (int j = 0; j < 4; ++j) acc[i][j] = (f32x4){0.f, 0.f, 0.f, 0.f};
  float m_[4], l_[4];
#pragma unroll
  for (int r = 0; r < 4; ++r) { m_[r] = -1e30f; l_[r] = 0.f; }

  for (int kt = 0; kt < 16; ++kt) {
    const int q0 = kt << 6;
    __syncthreads();  // (A) previous tile's LDS reads complete
    // ---- stage K tile: 64q x 64o bf16 (8 KB) ----
#pragma unroll
    for (int it = 0; it < 2; ++it) {
      int task = it * 256 + t;
      int q = task >> 3, oc = task & 7;
      bf16x8 v = *(const bf16x8*)(Kp + (((b << 10) + q0 + q) << 6) + (oc << 3));
      *(bf16x8*)(sK + ((q * 128 + oc * 16) ^ ((q & 7) << 4))) = v;
    }
    // ---- stage V tile: 256c x 64q fp32 -> bf16 (32 KB) ----
#pragma unroll
    for (int it = 0; it < 8; ++it) {
      int task = it * 256 + t;
      int c = task >> 3, qc = task & 7;
      const float* vp = kf + (((b << 8) + c) << 10) + q0 + (qc << 3);
      float4 f0 = *(const float4*)vp;
      float4 f1 = *(const float4*)(vp + 4);
      bf16x8 vb;
      vb[0] = (bf16)f0.x; vb[1] = (bf16)f0.y; vb[2] = (bf16)f0.z; vb[3] = (bf16)f0.w;
      vb[4] = (bf16)f1.x; vb[5] = (bf16)f1.y; vb[6] = (bf16)f1.z; vb[7] = (bf16)f1.w;
      *(bf16x8*)(sV + ((c * 128 + qc * 16) ^ ((c & 7) << 4))) = vb;
    }
    __syncthreads();  // (B) staging visible

    // ---- S = Q K^T for this wave's 16 rows ----
    f32x4 s[4];
#pragma unroll
    for (int qf = 0; qf < 4; ++qf) {
      int q = (qf << 4) + l16;
      bf16x8 k0 = *(const bf16x8*)(sK + ((q * 128 + g * 16) ^ ((q & 7) << 4)));
      bf16x8 k1 = *(const bf16x8*)(sK + ((q * 128 + g * 16 + 64) ^ ((q & 7) << 4)));
      f32x4 z4 = (f32x4){0.f, 0.f, 0.f, 0.f};
      z4 = MFMA16(aq0, k0, z4);
      s[qf] = MFMA16(aq1, k1, z4);
    }
    // ---- online softmax (rows 16w + 4g + r) ----
    float tm[4], sc[4], rs[4];
#pragma unroll
    for (int r = 0; r < 4; ++r) {
      tm[r] = fmaxf(fmaxf(s[0][r], s[1][r]), fmaxf(s[2][r], s[3][r]));
      tm[r] = fmaxf(tm[r], __shfl_xor(tm[r], 1));
      tm[r] = fmaxf(tm[r], __shfl_xor(tm[r], 2));
      tm[r] = fmaxf(tm[r], __shfl_xor(tm[r], 4));
      tm[r] = fmaxf(tm[r], __shfl_xor(tm[r], 8));
      float mn = fmaxf(m_[r], tm[r]);
      sc[r] = __expf(m_[r] - mn);
      m_[r] = mn;
    }
#pragma unroll
    for (int qf = 0; qf < 4; ++qf)
#pragma unroll
      for (int r = 0; r < 4; ++r) s[qf][r] = __expf(s[qf][r] - m_[r]);
#pragma unroll
    for (int r = 0; r < 4; ++r) {
      rs[r] = (s[0][r] + s[1][r]) + (s[2][r] + s[3][r]);
      rs[r] += __shfl_xor(rs[r], 1);
      rs[r] += __shfl_xor(rs[r], 2);
      rs[r] += __shfl_xor(rs[r], 4);
      rs[r] += __shfl_xor(rs[r], 8);
      l_[r] = l_[r] * sc[r] + rs[r];
    }
    // ---- publish P (bf16) and per-row rescale factors ----
    if (l16 == 0) {
#pragma unroll
      for (int r = 0; r < 4; ++r) sSc[(w << 4) + (g << 2) + r] = sc[r];
    }
#pragma unroll
    for (int qf = 0; qf < 4; ++qf)
#pragma unroll
      for (int r = 0; r < 4; ++r) {
        int row = (w << 4) + (g << 2) + r;
        int col = (qf << 4) + l16;
        *(bf16*)(sP + ((row * 128 + col * 2) ^ ((row & 7) << 4))) = (bf16)s[qf][r];
      }
    __syncthreads();  // (C) P + scales visible to all waves

    // ---- rescale accumulators ----
#pragma unroll
    for (int rg = 0; rg < 4; ++rg) {
      float f0 = sSc[(rg << 4) + (g << 2) + 0];
      float f1 = sSc[(rg << 4) + (g << 2) + 1];
      float f2 = sSc[(rg << 4) + (g << 2) + 2];
      float f3 = sSc[(rg << 4) + (g << 2) + 3];
#pragma unroll
      for (int cl = 0; cl < 4; ++cl) {
        acc[rg][cl][0] *= f0;
        acc[rg][cl][1] *= f1;
        acc[rg][cl][2] *= f2;
        acc[rg][cl][3] *= f3;
      }
    }
    // ---- load P A-fragments (all 64 rows) ----
    bf16x8 pa[4][2];
#pragma unroll
    for (int rg = 0; rg < 4; ++rg) {
      int row = (rg << 4) + l16;
      pa[rg][0] = *(const bf16x8*)(sP + ((row * 128 + g * 16) ^ ((row & 7) << 4)));
      pa[rg][1] = *(const bf16x8*)(sP + ((row * 128 + g * 16 + 64) ^ ((row & 7) << 4)));
    }
    // ---- PV: this wave's 64-channel slice ----
#pragma unroll
    for (int cl = 0; cl < 4; ++cl) {
      int c = (w << 6) + (cl << 4) + l16;
      bf16x8 v0 = *(const bf16x8*)(sV + ((c * 128 + g * 16) ^ ((c & 7) << 4)));
      bf16x8 v1 = *(const bf16x8*)(sV + ((c * 128 + g * 16 + 64) ^ ((c & 7) << 4)));
#pragma unroll
      for (int rg = 0; rg < 4; ++rg) {
        acc[rg][cl] = MFMA16(pa[rg][0], v0, acc[rg][cl]);
        acc[rg][cl] = MFMA16(pa[rg][1], v1, acc[rg][cl]);
      }
    }
  }

  // ---- epilogue: normalize, transpose via LDS, coalesced store ----
  if (l16 == 0) {
#pragma unroll
    for (int r = 0; r < 4; ++r) sL[(w << 4) + (g << 2) + r] = l_[r];
  }
  __syncthreads();  // also protects smem reuse below
  float* sO = (float*)smem;  // [c][65] padded
#pragma unroll
  for (int rg = 0; rg < 4; ++rg) {
    float i0 = 1.f / sL[(rg << 4) + (g << 2) + 0];
    float i1 = 1.f / sL[(rg << 4) + (g << 2) + 1];
    float i2 = 1.f / sL[(rg << 4) + (g << 2) + 2];
    float i3 = 1.f / sL[(rg << 4) + (g << 2) + 3];
    int rowb = (rg << 4) + (g << 2);
#pragma unroll
    for (int cl = 0; cl < 4; ++cl) {
      int c = (w << 6) + (cl << 4) + l16;
      sO[c * 65 + rowb + 0] = acc[rg][cl][0] * i0;
      sO[c * 65 + rowb + 1] = acc[rg][cl][1] * i1;
      sO[c * 65 + rowb + 2] = acc[rg][cl][2] * i2;
      sO[c * 65 + rowb + 3] = acc[rg][cl][3] * i3;
    }
  }
  __syncthreads();
#pragma unroll
  for (int it = 0; it < 16; ++it) {
    int c = (it << 4) + (t >> 4);
    int p4 = (t & 15) << 2;
    float4 v;
    v.x = sO[c * 65 + p4 + 0];
    v.y = sO[c * 65 + p4 + 1];
    v.z = sO[c * 65 + p4 + 2];
    v.w = sO[c * 65 + p4 + 3];
    *(float4*)(out + (((b << 8) + c) << 10) + p0 + p4) = v;
  }
}

// ---------------------------------------------------------------------------
extern "C" void kernel_launch(void* const* d_in, const int* in_sizes, int n_in,
                              void* d_out, int out_size, void* d_ws, size_t ws_size,
                              hipStream_t stream) {
  const float* qf = (const float*)d_in[0];
  const float* kf = (const float*)d_in[1];
  const float* Wq = (const float*)d_in[2];
  const float* bq = (const float*)d_in[3];
  const float* Wk = (const float*)d_in[4];
  const float* bk = (const float*)d_in[5];
  // d_in[6] = vis_CA (unused)
  const int* flag = (const int*)d_in[7];  // same_WqWk
  float* out = (float*)d_out;

  char* ws = (char*)d_ws;
  bf16* Qp = (bf16*)ws;                          // 4 MiB: [32][1024][64] bf16
  bf16* Kp = (bf16*)(ws + (4u << 20));           // 4 MiB
  bf16* Wbh = (bf16*)(ws + (8u << 20));          // 64 KiB: [2][64][256] bf16
  bf16* Wbl = (bf16*)(ws + (8u << 20) + 65536);  // 64 KiB

  prep_w_kernel<<<dim3(16, 2), 256, 0, stream>>>(Wq, Wk, flag, Wbh, Wbl);
  proj_kernel<<<dim3(8, 32, 2), 256, 0, stream>>>(qf, kf, Wbh, Wbl, bq, bk, flag, Qp, Kp);
  attn_kernel<<<dim3(16, 32), 256, 0, stream>>>(kf, Qp, Kp, out);
}